// Round 8
// baseline (246.793 us; speedup 1.0000x reference)
//
#include <hip/hip_runtime.h>
#include <math.h>

#define NN 512
#define KP 64
#define NPANEL 8
#define NTHR 256
#define NBLK 256
#define TRUNITS (448 * 112)

// LDS float offsets (25728 floats = 100.5 KB -> 1 block/CU).
// Strides: 65 for scalar-read-by-row tiles (D,V), 68 for float4-aligned
// staged tiles (68%32=4 -> stride-4-row scalar reads land in distinct banks).
#define D_   0        // 64 x 65   diag block (state p)
#define V_   4160     // 64 x 65   V-state for substitution
#define B2_  8320     // 64 x 68   Cprev k0-rows tile
#define UB_  12672    // 64 x 68   Rprev k0-cols tile
#define SB_  17024    // 64 x 68   own-slice prev tile
#define H_   21376    // 64 x 68   evolve snapshot history
#define LDSN 25728

__device__ __forceinline__ float einit(const float* s, const float* dI, int i, int j) {
  float w = dI[i * NN + j] / (s[i * NN + j] + 1e-4f);
  if (i == j) w = 0.f;
  return expf(-10.f * w);
}

// Launch 0: panel work for p=0 ONLY (32 blocks). Writes just C0/R0 (256 KB)
// so it overlaps the harness's ws-poison HBM drain with pure compute.
// E is NOT initialized here — phase 1 fuses einit into its updates.
__global__ __launch_bounds__(NTHR) void fw_p0(
    const float* __restrict__ s, const float* __restrict__ dI,
    float* __restrict__ Cs, float* __restrict__ Rs, float* __restrict__ out) {
  __shared__ __align__(16) float lds[LDSN];
  const int blk = blockIdx.x, tid = threadIdx.x;
  const bool isC = (blk < 16);
  const int sb = (blk >> 1) & 7;
  const int h = blk & 1;
  const int sOff = sb * KP;
  const bool haveSl = (sb != 0);
  if (blk == 0 && tid == 0) out[0] = 0.f;

  // einit diag -> D ; einit own slice -> V (solve-dim-major)
  for (int e = tid; e < 4096; e += NTHR) {
    const int a = e >> 6, b = e & 63;
    lds[D_ + a * 65 + b] = einit(s, dI, a, b);
  }
  if (haveSl) {
    if (isC) {
      for (int e = tid; e < 2048; e += NTHR) {
        const int a = 32 * h + (e >> 6), b = e & 63;
        lds[V_ + a * 65 + b] = einit(s, dI, sOff + a, b);
      }
    } else {
      for (int e = tid; e < 2048; e += NTHR) {
        const int m = e >> 5, j = 32 * h + (e & 31);
        lds[V_ + j * 65 + m] = einit(s, dI, m, sOff + j);
      }
    }
  }
  __syncthreads();

  // concurrent: wave0 readlane evolve || waves1-2 V=D/D^T for diag slices
  if (tid < 64) {
    float x[64];
    if (isC) {
#pragma unroll
      for (int a = 0; a < 64; ++a) x[a] = lds[D_ + a * 65 + tid];
    } else {
#pragma unroll
      for (int a = 0; a < 64; ++a) x[a] = lds[D_ + tid * 65 + a];
    }
#pragma unroll
    for (int m = 0; m < 64; ++m) {
      const float xm = x[m];
      lds[H_ + m * 68 + tid] = xm;
#pragma unroll
      for (int a = 0; a < 64; ++a) {
        const int sa = __builtin_amdgcn_readlane(__float_as_int(x[a]), m);
        x[a] += __int_as_float(sa) * xm;
      }
    }
  } else if (tid < 192) {
    if (!haveSl) {
      for (int e = tid - 64; e < 4096; e += 128) {
        const int a = e >> 6, b = e & 63;
        lds[V_ + a * 65 + b] = isC ? lds[D_ + a * 65 + b] : lds[D_ + b * 65 + a];
      }
    }
  }
  __syncthreads();

  // chunked forward substitution on V rows [32h, 32h+32)
  for (int cch = 0; cch < 4; ++cch) {
    const int mb = cch * 16;
    if (cch > 0 && tid < 128) {
      const int r = 32 * h + (tid & 31);
      const int g = tid >> 5;
      const int m0c = mb + 4 * g;
      const int vb = V_ + r * 65;
      float a0 = lds[vb + m0c + 0], a1 = lds[vb + m0c + 1];
      float a2 = lds[vb + m0c + 2], a3 = lds[vb + m0c + 3];
      for (int mp = 0; mp < mb; ++mp) {
        const float vr = lds[vb + mp];
        const float4 u4 = *(const float4*)&lds[H_ + mp * 68 + m0c];
        a0 += vr * u4.x; a1 += vr * u4.y; a2 += vr * u4.z; a3 += vr * u4.w;
      }
      lds[vb + m0c + 0] = a0; lds[vb + m0c + 1] = a1;
      lds[vb + m0c + 2] = a2; lds[vb + m0c + 3] = a3;
    }
    __syncthreads();
    if (tid < 32) {
      const int r = 32 * h + tid;
      const int vb = V_ + r * 65 + mb;
      float v[16];
#pragma unroll
      for (int u2 = 0; u2 < 16; ++u2) v[u2] = lds[vb + u2];
#pragma unroll
      for (int mp = 0; mp < 15; ++mp) {
        const float vmp = v[mp];
#pragma unroll
        for (int m2 = mp + 1; m2 < 16; ++m2)
          v[m2] += vmp * lds[H_ + (mb + mp) * 68 + (mb + m2)];
      }
#pragma unroll
      for (int u2 = 0; u2 < 16; ++u2) lds[vb + u2] = v[u2];
    }
    __syncthreads();
  }

  // snapshot writeout (panel 0)
  if (isC) {
    for (int e = tid; e < 2048; e += NTHR) {
      const int a = 32 * h + (e >> 6), b = e & 63;
      Cs[(size_t)(sOff + a) * KP + b] = lds[V_ + a * 65 + b];
    }
  } else {
    for (int e = tid; e < 2048; e += NTHR) {
      const int m = e >> 5, j = 32 * h + (e & 31);
      Rs[(size_t)m * NN + (sOff + j)] = lds[V_ + j * 65 + m];
    }
  }
}

// Phase p in 1..7. p==1 fuses E's einit base into every E update.
__global__ __launch_bounds__(NTHR) void fw_phase(
    const float* __restrict__ s, const float* __restrict__ dI,
    float* __restrict__ E, float* __restrict__ Cs, float* __restrict__ Rs,
    int p) {
  __shared__ __align__(16) float lds[LDSN];
  const int blk = blockIdx.x, tid = threadIdx.x;
  const int k0 = p * KP;
  const float* Cprev = Cs + (size_t)(p - 1) * (NN * KP);
  const float* Rprev = Rs + (size_t)(p - 1) * (KP * NN);

  if (blk >= 32) {
    // ================= trailing blocks =================
    const int gt = (blk - 32) * NTHR + tid;
    if (gt >= TRUNITS) return;
    const int ii = gt / 112;
    const int jj = gt - ii * 112;
    const int i = (ii < k0) ? ii : ii + KP;
    const int j = ((jj < (p << 4)) ? jj : jj + 16) << 2;
    const int idx = i * NN + j;
    float4 acc;
    if (p == 1) {   // fused init: base = einit(s,d)
      acc.x = einit(s, dI, i, j + 0);
      acc.y = einit(s, dI, i, j + 1);
      acc.z = einit(s, dI, i, j + 2);
      acc.w = einit(s, dI, i, j + 3);
    } else {
      acc = *(const float4*)(E + idx);
    }
    const float* crow = Cprev + (size_t)i * KP;
    const float* rcol = Rprev + j;
#pragma unroll 8
    for (int r = 0; r < KP; ++r) {
      const float cv = crow[r];
      const float4 rv = *(const float4*)(rcol + (size_t)r * NN);
      acc.x += cv * rv.x; acc.y += cv * rv.y;
      acc.z += cv * rv.z; acc.w += cv * rv.w;
    }
    *(float4*)(E + idx) = acc;
    return;
  }

  // ================= panel blocks =================
  const bool isC = (blk < 16);
  const int sb = (blk >> 1) & 7;
  const int h = blk & 1;                 // half: rows/cols [32h, 32h+32)
  const int sOff = sb * KP;
  const bool haveSl = (sb != p);

  // prefetch diag base (independent of LDS staging)
  const int r0d = (tid >> 4) << 2, m0d = (tid & 15) << 2;
  float4 epre[4];
  if (p == 1) {
#pragma unroll
    for (int i2 = 0; i2 < 4; ++i2) {
      epre[i2].x = einit(s, dI, k0 + r0d + i2, k0 + m0d + 0);
      epre[i2].y = einit(s, dI, k0 + r0d + i2, k0 + m0d + 1);
      epre[i2].z = einit(s, dI, k0 + r0d + i2, k0 + m0d + 2);
      epre[i2].w = einit(s, dI, k0 + r0d + i2, k0 + m0d + 3);
    }
  } else {
#pragma unroll
    for (int i2 = 0; i2 < 4; ++i2)
      epre[i2] = *(const float4*)(E + (size_t)(k0 + r0d + i2) * NN + (k0 + m0d));
  }

  // -------- stage tiles (float4, stride-68) --------
#pragma unroll
  for (int k = 0; k < 4; ++k) {
    const int e4 = tid + k * NTHR;
    const int a = e4 >> 4, b4 = (e4 & 15) << 2;
    *(float4*)&lds[B2_ + a * 68 + b4] =
        *(const float4*)(Cprev + (size_t)(k0 + a) * KP + b4);
    *(float4*)&lds[UB_ + a * 68 + b4] =
        *(const float4*)(Rprev + (size_t)a * NN + (k0 + b4));
    if (haveSl) {
      if (isC)
        *(float4*)&lds[SB_ + a * 68 + b4] =
            *(const float4*)(Cprev + (size_t)(sOff + a) * KP + b4);
      else
        *(float4*)&lds[SB_ + a * 68 + b4] =
            *(const float4*)(Rprev + (size_t)a * NN + (sOff + b4));
    }
  }
  __syncthreads();

  // -------- diag GEMM: D = base + Ck0 * Rk0 (state p) --------
  {
    float acc[4][4];
#pragma unroll
    for (int i2 = 0; i2 < 4; ++i2) {
      acc[i2][0] = epre[i2].x; acc[i2][1] = epre[i2].y;
      acc[i2][2] = epre[i2].z; acc[i2][3] = epre[i2].w;
    }
    for (int rr = 0; rr < KP; ++rr) {
      const float4 b4 = *(const float4*)&lds[UB_ + rr * 68 + m0d];
#pragma unroll
      for (int i2 = 0; i2 < 4; ++i2) {
        const float av = lds[B2_ + (r0d + i2) * 68 + rr];
        acc[i2][0] += av * b4.x; acc[i2][1] += av * b4.y;
        acc[i2][2] += av * b4.z; acc[i2][3] += av * b4.w;
      }
    }
#pragma unroll
    for (int i2 = 0; i2 < 4; ++i2)
#pragma unroll
      for (int j2 = 0; j2 < 4; ++j2)
        lds[D_ + (r0d + i2) * 65 + (m0d + j2)] = acc[i2][j2];
  }
  __syncthreads();

  // ======== concurrent region: wave0 evolve || waves1-2 slice GEMM ========
  if (tid < 64) {
    // barrier-free readlane evolve (R-side evolves the transpose)
    float x[64];
    if (isC) {
#pragma unroll
      for (int a = 0; a < 64; ++a) x[a] = lds[D_ + a * 65 + tid];
    } else {
#pragma unroll
      for (int a = 0; a < 64; ++a) x[a] = lds[D_ + tid * 65 + a];
    }
#pragma unroll
    for (int m = 0; m < 64; ++m) {
      const float xm = x[m];
      lds[H_ + m * 68 + tid] = xm;
#pragma unroll
      for (int a = 0; a < 64; ++a) {
        const int sa = __builtin_amdgcn_readlane(__float_as_int(x[a]), m);
        x[a] += __int_as_float(sa) * xm;
      }
    }
  } else if (tid < 192) {
    const int tt = tid - 64;
    if (haveSl) {
      // slice GEMM: V = base + prev rank-64; write corrected E back
      float acc[4][4];
      if (isC) {
        const int r0 = 32 * h + ((tt >> 4) << 2);
        const int m0 = (tt & 15) << 2;
        if (p == 1) {
#pragma unroll
          for (int i2 = 0; i2 < 4; ++i2) {
            acc[i2][0] = einit(s, dI, sOff + r0 + i2, k0 + m0 + 0);
            acc[i2][1] = einit(s, dI, sOff + r0 + i2, k0 + m0 + 1);
            acc[i2][2] = einit(s, dI, sOff + r0 + i2, k0 + m0 + 2);
            acc[i2][3] = einit(s, dI, sOff + r0 + i2, k0 + m0 + 3);
          }
        } else {
#pragma unroll
          for (int i2 = 0; i2 < 4; ++i2) {
            const float4 ev = *(const float4*)(E + (size_t)(sOff + r0 + i2) * NN + (k0 + m0));
            acc[i2][0] = ev.x; acc[i2][1] = ev.y; acc[i2][2] = ev.z; acc[i2][3] = ev.w;
          }
        }
        for (int rr = 0; rr < KP; ++rr) {
          const float4 b4 = *(const float4*)&lds[UB_ + rr * 68 + m0];
#pragma unroll
          for (int i2 = 0; i2 < 4; ++i2) {
            const float av = lds[SB_ + (r0 + i2) * 68 + rr];
            acc[i2][0] += av * b4.x; acc[i2][1] += av * b4.y;
            acc[i2][2] += av * b4.z; acc[i2][3] += av * b4.w;
          }
        }
#pragma unroll
        for (int i2 = 0; i2 < 4; ++i2) {
          *(float4*)(E + (size_t)(sOff + r0 + i2) * NN + (k0 + m0)) =
              make_float4(acc[i2][0], acc[i2][1], acc[i2][2], acc[i2][3]);
#pragma unroll
          for (int j2 = 0; j2 < 4; ++j2)
            lds[V_ + (r0 + i2) * 65 + (m0 + j2)] = acc[i2][j2];
        }
      } else {
        const int r0 = (tt & 15) << 2;              // m rows k0+r0..
        const int c0 = 32 * h + ((tt >> 4) << 2);   // slice col band
        if (p == 1) {
#pragma unroll
          for (int i2 = 0; i2 < 4; ++i2) {
            acc[i2][0] = einit(s, dI, k0 + r0 + i2, sOff + c0 + 0);
            acc[i2][1] = einit(s, dI, k0 + r0 + i2, sOff + c0 + 1);
            acc[i2][2] = einit(s, dI, k0 + r0 + i2, sOff + c0 + 2);
            acc[i2][3] = einit(s, dI, k0 + r0 + i2, sOff + c0 + 3);
          }
        } else {
#pragma unroll
          for (int i2 = 0; i2 < 4; ++i2) {
            const float4 ev = *(const float4*)(E + (size_t)(k0 + r0 + i2) * NN + (sOff + c0));
            acc[i2][0] = ev.x; acc[i2][1] = ev.y; acc[i2][2] = ev.z; acc[i2][3] = ev.w;
          }
        }
        for (int rr = 0; rr < KP; ++rr) {
          const float4 b4 = *(const float4*)&lds[SB_ + rr * 68 + c0];
#pragma unroll
          for (int i2 = 0; i2 < 4; ++i2) {
            const float av = lds[B2_ + (r0 + i2) * 68 + rr];
            acc[i2][0] += av * b4.x; acc[i2][1] += av * b4.y;
            acc[i2][2] += av * b4.z; acc[i2][3] += av * b4.w;
          }
        }
#pragma unroll
        for (int i2 = 0; i2 < 4; ++i2) {
          *(float4*)(E + (size_t)(k0 + r0 + i2) * NN + (sOff + c0)) =
              make_float4(acc[i2][0], acc[i2][1], acc[i2][2], acc[i2][3]);
#pragma unroll
          for (int j2 = 0; j2 < 4; ++j2)
            lds[V_ + (c0 + j2) * 65 + (r0 + i2)] = acc[i2][j2];
        }
      }
    } else {
      // diag slice: V = D (C-side) or D^T (R-side)
      for (int e = tt; e < 4096; e += 128) {
        const int a = e >> 6, b = e & 63;
        lds[V_ + a * 65 + b] = isC ? lds[D_ + a * 65 + b] : lds[D_ + b * 65 + a];
      }
    }
  } else {
    // threads 192..255: at p==1, sb==1 C-side blocks write E[diag(1,1)] base
    // (= plain einit; its missing C0R0 term is k_loss's diag fixup)
    if (p == 1 && !haveSl && isC) {
      for (int e = 2048 * h + (tid - 192); e < 2048 * (h + 1); e += 64) {
        const int a = e >> 6, b = e & 63;
        E[(size_t)(k0 + a) * NN + (k0 + b)] = einit(s, dI, k0 + a, k0 + b);
      }
    }
  }
  __syncthreads();

  // -------- chunked forward substitution on V rows [32h, 32h+32) ------
  for (int cch = 0; cch < 4; ++cch) {
    const int mb = cch * 16;
    if (cch > 0 && tid < 128) {
      const int r = 32 * h + (tid & 31);
      const int g = tid >> 5;
      const int m0c = mb + 4 * g;
      const int vb = V_ + r * 65;
      float a0 = lds[vb + m0c + 0], a1 = lds[vb + m0c + 1];
      float a2 = lds[vb + m0c + 2], a3 = lds[vb + m0c + 3];
      for (int mp = 0; mp < mb; ++mp) {
        const float vr = lds[vb + mp];
        const float4 u4 = *(const float4*)&lds[H_ + mp * 68 + m0c];
        a0 += vr * u4.x; a1 += vr * u4.y; a2 += vr * u4.z; a3 += vr * u4.w;
      }
      lds[vb + m0c + 0] = a0; lds[vb + m0c + 1] = a1;
      lds[vb + m0c + 2] = a2; lds[vb + m0c + 3] = a3;
    }
    __syncthreads();
    if (tid < 32) {
      const int r = 32 * h + tid;
      const int vb = V_ + r * 65 + mb;
      float v[16];
#pragma unroll
      for (int u2 = 0; u2 < 16; ++u2) v[u2] = lds[vb + u2];
#pragma unroll
      for (int mp = 0; mp < 15; ++mp) {
        const float vmp = v[mp];
#pragma unroll
        for (int m2 = mp + 1; m2 < 16; ++m2)
          v[m2] += vmp * lds[H_ + (mb + mp) * 68 + (mb + m2)];
      }
#pragma unroll
      for (int u2 = 0; u2 < 16; ++u2) lds[vb + u2] = v[u2];
    }
    __syncthreads();
  }

  // -------- snapshot panel writeout --------
  float* Cp = Cs + (size_t)p * (NN * KP);
  float* Rp = Rs + (size_t)p * (KP * NN);
  if (isC) {
    for (int e = tid; e < 2048; e += NTHR) {
      const int a = 32 * h + (e >> 6), b = e & 63;
      Cp[(size_t)(sOff + a) * KP + b] = lds[V_ + a * 65 + b];
    }
  } else {
    for (int e = tid; e < 2048; e += NTHR) {
      const int m = e >> 5, j = 32 * h + (e & 31);
      Rp[(size_t)m * NN + (sOff + j)] = lds[V_ + j * 65 + m];
    }
  }
}

__device__ __forceinline__ float loss_elem(float Ev, float sv, float ov,
                                           float dv, float fv, int i, int j,
                                           float esc) {
  const float sp = (Ev > 0.f) ? (-0.1f * logf(Ev)) : 1e9f;
  const float ur = expf(-0.005f * sp);
  const float ub = expf(-0.01f * dv);
  const float choice = ur / (ur + ub);
  const float ug = fv * choice * (dv - 0.5f * sp);
  const float util = (ug > 0.f) ? (ug + 1.f) : expf(ug);  // elu + 1
  const float ent = sv * (((i == j) ? 1.f : 0.f) - sv);
  return sv * dv + util + esc * ent * ent + 10000.f * (sv * (1.f - ov));
}

// Final pass: E + C7*R7 (+ diag fixup C_{b-1}R_{b-1}) -> fused loss reduce.
__global__ __launch_bounds__(NTHR) void k_loss(
    const float* __restrict__ s, const float* __restrict__ o,
    const float* __restrict__ dI, const float* __restrict__ f,
    const int* __restrict__ ep, const float* __restrict__ E,
    const float* __restrict__ Cs, const float* __restrict__ Rs,
    float* __restrict__ out) {
  __shared__ float red[NTHR];
  const int tid = threadIdx.x;
  const int g = blockIdx.x * NTHR + tid;
  const int idx0 = g * 4;
  const int i = idx0 >> 9;
  const int j = idx0 & (NN - 1);
  const float* C7 = Cs + (size_t)7 * (NN * KP);
  const float* R7 = Rs + (size_t)7 * (KP * NN);
  float4 acc = *(const float4*)(E + idx0);
  {
    const float* crow = C7 + (size_t)i * KP;
    const float* rcol = R7 + j;
#pragma unroll 8
    for (int r = 0; r < KP; ++r) {
      const float cv = crow[r];
      const float4 rv = *(const float4*)(rcol + (size_t)r * NN);
      acc.x += cv * rv.x; acc.y += cv * rv.y;
      acc.z += cv * rv.z; acc.w += cv * rv.w;
    }
  }
  const int bi = i >> 6, bj = j >> 6;
  if (bi == bj && bi >= 1) {   // diag block: add the skipped C_{b-1}R_{b-1}
    const float* cf = Cs + (size_t)(bi - 1) * (NN * KP) + (size_t)i * KP;
    const float* rf = Rs + (size_t)(bi - 1) * (KP * NN) + j;
#pragma unroll 8
    for (int r = 0; r < KP; ++r) {
      const float cv = cf[r];
      const float4 rv = *(const float4*)(rf + (size_t)r * NN);
      acc.x += cv * rv.x; acc.y += cv * rv.y;
      acc.z += cv * rv.z; acc.w += cv * rv.w;
    }
  }
  const float4 sv = *(const float4*)(s + idx0);
  const float4 ov = *(const float4*)(o + idx0);
  const float4 dv = *(const float4*)(dI + idx0);
  const float4 fv = *(const float4*)(f + idx0);
  const int e = ep[0];
  const float esc = (e < 0) ? 0.f : (e < 10) ? 0.05f : (e < 50) ? 0.1f : 1.f;
  float lsum = loss_elem(acc.x, sv.x, ov.x, dv.x, fv.x, i, j + 0, esc)
             + loss_elem(acc.y, sv.y, ov.y, dv.y, fv.y, i, j + 1, esc)
             + loss_elem(acc.z, sv.z, ov.z, dv.z, fv.z, i, j + 2, esc)
             + loss_elem(acc.w, sv.w, ov.w, dv.w, fv.w, i, j + 3, esc);
  red[tid] = lsum;
  __syncthreads();
#pragma unroll
  for (int st = 128; st > 0; st >>= 1) {
    if (tid < st) red[tid] += red[tid + st];
    __syncthreads();
  }
  if (tid == 0) atomicAdd(out, red[0]);
}

extern "C" void kernel_launch(void* const* d_in, const int* in_sizes, int n_in,
                              void* d_out, int out_size, void* d_ws, size_t ws_size,
                              hipStream_t stream) {
  const float* s = (const float*)d_in[0];   // soft_adj
  const float* o = (const float*)d_in[1];   // original_adj
  const float* d = (const float*)d_in[2];   // distances
  const float* f = (const float*)d_in[3];   // flow
  const int* ep = (const int*)d_in[4];      // epoch

  float* E = (float*)d_ws;                  // 512*512
  float* Cs = E + NN * NN;                  // 8 x [512*64]
  float* Rs = Cs + NPANEL * NN * KP;        // 8 x [64*512]
  float* out = (float*)d_out;

  fw_p0<<<32, NTHR, 0, stream>>>(s, d, Cs, Rs, out);
  for (int p = 1; p < NPANEL; ++p)
    fw_phase<<<NBLK, NTHR, 0, stream>>>(s, d, E, Cs, Rs, p);
  k_loss<<<NBLK, NTHR, 0, stream>>>(s, o, d, f, ep, E, Cs, Rs, out);
}